// Round 1
// baseline (134.849 us; speedup 1.0000x reference)
//
#include <hip/hip_runtime.h>

// StatefulFormantFilter: B=32, T=48000, F=5
// y[t] = x[t] + 2 r cos(th) y[t-1] - r^2 y[t-2],  r=exp(-pi bw/SR), th=2 pi cf/SR
// x = excitation * (1-r^2) sin(th)
// out[b,t] = sum_f y[b,t,f];  new_states[b,f,:] = (y[T-1], y[T-2])
//
// Chunked affine-scan: state s=(y1,y2); per chunk s_out = A s_in + w.
// Pass1: per (b,f,chunk) compute A (2 columns via unit-state recurrences) and w.
// Pass2: per (b,f) sequential compose over chunks; store entering state per chunk;
//        final state -> new_states output.
// Pass3: per (b,chunk) replay all 5 formants with correct initial states, sum, store.

constexpr int B = 32;
constexpr int T = 48000;
constexpr int F = 5;
constexpr int L = 64;         // chunk length
constexpr int C = T / L;      // 750 chunks per chain

// exp(-pi*bw/SR) = exp2( (-pi/(SR*ln2)) * bw )
#define CBW2 (-9.4416635e-05f)   // -pi/(48000*ln2)
#define CCF  (1.3089969e-04f)    // 2*pi/48000

__global__ __launch_bounds__(256) void pass1_kernel(
    const float* __restrict__ exc, const float* __restrict__ cf,
    const float* __restrict__ bw, float* __restrict__ Aws) {
  int tid = blockIdx.x * blockDim.x + threadIdx.x;
  if (tid >= B * C * F) return;
  int f = tid % F;
  int c = (tid / F) % C;
  int b = tid / (F * C);

  // A columns: u = response to (1,0), v = response to (0,1); w = driven response
  float u1 = 1.f, u2 = 0.f;
  float v1 = 0.f, v2 = 1.f;
  float w1 = 0.f, w2 = 0.f;

  int t0 = c * L;
  const float* cfp = cf + (size_t)(b * T + t0) * F + f;
  const float* bwp = bw + (size_t)(b * T + t0) * F + f;
  const float* ep  = exc + (size_t)b * T + t0;

  #pragma unroll 4
  for (int i = 0; i < L; ++i) {
    float bwf = bwp[(size_t)i * F];
    float cff = cfp[(size_t)i * F];
    float e   = ep[i];
    float r  = exp2f(CBW2 * bwf);
    float th = CCF * cff;
    float sn = __sinf(th);
    float cs = __cosf(th);
    float p = 2.f * r * cs;     // = -a1
    float q = -r * r;           // = -a2
    float g = fmaf(q, sn, sn);  // (1 - r^2) sin(th)
    float x = e * g;
    float nu = fmaf(p, u1, q * u2);
    float nv = fmaf(p, v1, q * v2);
    float nw = fmaf(p, w1, fmaf(q, w2, x));
    u2 = u1; u1 = nu;
    v2 = v1; v1 = nv;
    w2 = w1; w1 = nw;
  }
  float* o = Aws + (size_t)((c * B + b) * F + f) * 6;
  o[0] = u1; o[1] = u2;
  o[2] = v1; o[3] = v2;
  o[4] = w1; o[5] = w2;
}

__global__ __launch_bounds__(64) void pass2_kernel(
    const float* __restrict__ Aws, const float* __restrict__ states0,
    float* __restrict__ Sws, float* __restrict__ out_states) {
  int tid = blockIdx.x * blockDim.x + threadIdx.x;
  if (tid >= B * F) return;   // tid = b*F + f
  float y1 = states0[tid * 2 + 0];
  float y2 = states0[tid * 2 + 1];
  for (int c = 0; c < C; ++c) {
    float* s = Sws + (size_t)(c * B * F + tid) * 2;
    s[0] = y1; s[1] = y2;
    const float* a = Aws + (size_t)(c * B * F + tid) * 6;
    float u1 = a[0], u2 = a[1], v1 = a[2], v2 = a[3], w1 = a[4], w2 = a[5];
    float ny1 = fmaf(u1, y1, fmaf(v1, y2, w1));
    float ny2 = fmaf(u2, y1, fmaf(v2, y2, w2));
    y1 = ny1; y2 = ny2;
  }
  out_states[tid * 2 + 0] = y1;
  out_states[tid * 2 + 1] = y2;
}

__global__ __launch_bounds__(256) void pass3_kernel(
    const float* __restrict__ exc, const float* __restrict__ cf,
    const float* __restrict__ bw, const float* __restrict__ Sws,
    float* __restrict__ out) {
  int tid = blockIdx.x * blockDim.x + threadIdx.x;
  if (tid >= B * C) return;
  int c = tid % C;
  int b = tid / C;

  float y1[F], y2[F];
  #pragma unroll
  for (int f = 0; f < F; ++f) {
    const float* s = Sws + (size_t)((c * B * F) + b * F + f) * 2;
    y1[f] = s[0];
    y2[f] = s[1];
  }

  int t0 = c * L;
  const float* cfp = cf + (size_t)(b * T + t0) * F;
  const float* bwp = bw + (size_t)(b * T + t0) * F;
  const float* ep  = exc + (size_t)b * T + t0;
  float* op        = out + (size_t)b * T + t0;

  #pragma unroll 2
  for (int i = 0; i < L; ++i) {
    float e = ep[i];
    float sum = 0.f;
    #pragma unroll
    for (int f = 0; f < F; ++f) {
      float bwf = bwp[(size_t)i * F + f];
      float cff = cfp[(size_t)i * F + f];
      float r  = exp2f(CBW2 * bwf);
      float th = CCF * cff;
      float sn = __sinf(th);
      float cs = __cosf(th);
      float p = 2.f * r * cs;
      float q = -r * r;
      float g = fmaf(q, sn, sn);
      float x = e * g;
      float y = fmaf(p, y1[f], fmaf(q, y2[f], x));
      sum += y;
      y2[f] = y1[f];
      y1[f] = y;
    }
    op[i] = sum;
  }
}

extern "C" void kernel_launch(void* const* d_in, const int* in_sizes, int n_in,
                              void* d_out, int out_size, void* d_ws, size_t ws_size,
                              hipStream_t stream) {
  const float* exc = (const float*)d_in[0];   // (B,T,1)
  const float* cf  = (const float*)d_in[1];   // (B,T,F)
  const float* bw  = (const float*)d_in[2];   // (B,T,F)
  const float* st  = (const float*)d_in[3];   // (B,F,2)
  float* out        = (float*)d_out;          // (B,T,1) then (B,F,2)
  float* out_states = out + (size_t)B * T;

  float* Aws = (float*)d_ws;                        // C*B*F*6 floats = 2.88 MB
  float* Sws = Aws + (size_t)C * B * F * 6;         // C*B*F*2 floats = 0.96 MB

  int n1 = B * C * F;
  pass1_kernel<<<(n1 + 255) / 256, 256, 0, stream>>>(exc, cf, bw, Aws);
  int n2 = B * F;
  pass2_kernel<<<(n2 + 63) / 64, 64, 0, stream>>>(Aws, st, Sws, out_states);
  int n3 = B * C;
  pass3_kernel<<<(n3 + 255) / 256, 256, 0, stream>>>(exc, cf, bw, Sws, out);
}

// Round 2
// 90.206 us; speedup vs baseline: 1.4949x; 1.4949x over previous
//
#include <hip/hip_runtime.h>

// StatefulFormantFilter: B=32, T=48000, F=5
// y[t] = x[t] + 2 r cos(th) y[t-1] - r^2 y[t-2],  r=exp(-pi bw/SR), th=2 pi cf/SR
// x = excitation * (1-r^2) sin(th)
// out[b,t] = sum_f y[b,t,f];  new_states[b,f,:] = (y[T-1], y[T-2])
//
// Chunked affine-scan: state s=(y1,y2); per chunk s_out = A s_in + w.
// Pass1: per (b,f,chunk) compute A (2 columns via unit-state recurrences) and w.
//        Aws layout: chain-major [chain][c][8] (6 used, padded for float4).
// Pass2: one WAVE per chain; Hillis-Steele scan of affine maps over 64-chunk
//        groups (6 shuffle-compose steps), sequential only across 12 groups.
// Pass3: per (b,chunk) replay all 5 formants with correct initial states, sum.

constexpr int B = 32;
constexpr int T = 48000;
constexpr int F = 5;
constexpr int L = 64;         // chunk length
constexpr int C = T / L;      // 750 chunks per chain
constexpr int NG = (C + 63) / 64;  // 12 scan groups

// exp(-pi*bw/SR) = exp2( (-pi/(SR*ln2)) * bw )
#define CBW2 (-9.4416635e-05f)   // -pi/(48000*ln2)
#define CCF  (1.3089969e-04f)    // 2*pi/48000

__global__ __launch_bounds__(256) void pass1_kernel(
    const float* __restrict__ exc, const float* __restrict__ cf,
    const float* __restrict__ bw, float* __restrict__ Aws) {
  int tid = blockIdx.x * blockDim.x + threadIdx.x;
  if (tid >= B * C * F) return;
  int f = tid % F;
  int c = (tid / F) % C;
  int b = tid / (F * C);

  // A columns: u = response to (1,0), v = response to (0,1); w = driven response
  float u1 = 1.f, u2 = 0.f;
  float v1 = 0.f, v2 = 1.f;
  float w1 = 0.f, w2 = 0.f;

  int t0 = c * L;
  const float* cfp = cf + (size_t)(b * T + t0) * F + f;
  const float* bwp = bw + (size_t)(b * T + t0) * F + f;
  const float* ep  = exc + (size_t)b * T + t0;

  #pragma unroll 8
  for (int i = 0; i < L; ++i) {
    float bwf = bwp[(size_t)i * F];
    float cff = cfp[(size_t)i * F];
    float e   = ep[i];
    float r  = exp2f(CBW2 * bwf);
    float th = CCF * cff;
    float sn = __sinf(th);
    float cs = __cosf(th);
    float p = 2.f * r * cs;     // = -a1
    float q = -r * r;           // = -a2
    float g = fmaf(q, sn, sn);  // (1 - r^2) sin(th)
    float x = e * g;
    float nu = fmaf(p, u1, q * u2);
    float nv = fmaf(p, v1, q * v2);
    float nw = fmaf(p, w1, fmaf(q, w2, x));
    u2 = u1; u1 = nu;
    v2 = v1; v1 = nv;
    w2 = w1; w1 = nw;
  }
  int chain = b * F + f;
  float4* o = (float4*)(Aws + ((size_t)chain * C + c) * 8);
  o[0] = make_float4(u1, u2, v1, v2);
  o[1] = make_float4(w1, w2, 0.f, 0.f);
}

__global__ __launch_bounds__(64) void pass2_kernel(
    const float* __restrict__ Aws, const float* __restrict__ states0,
    float* __restrict__ Sws, float* __restrict__ out_states) {
  int chain = blockIdx.x;        // 160 chains, one wave each
  int lane = threadIdx.x;

  const float4* base = (const float4*)Aws + (size_t)chain * C * 2;
  float cy1 = states0[chain * 2 + 0];
  float cy2 = states0[chain * 2 + 1];

  // prefetch group 0
  int cp = lane < C ? lane : C - 1;
  float4 A0 = base[cp * 2 + 0];
  float4 A1 = base[cp * 2 + 1];

  for (int g = 0; g < NG; ++g) {
    int c = g * 64 + lane;
    bool valid = c < C;
    float u1, u2, v1, v2, w1, w2;
    if (valid) { u1 = A0.x; u2 = A0.y; v1 = A0.z; v2 = A0.w; w1 = A1.x; w2 = A1.y; }
    else       { u1 = 1.f;  u2 = 0.f;  v1 = 0.f;  v2 = 1.f;  w1 = 0.f;  w2 = 0.f; }

    // prefetch next group while scanning this one
    if (g + 1 < NG) {
      int cn = c + 64; if (cn > C - 1) cn = C - 1;
      A0 = base[cn * 2 + 0];
      A1 = base[cn * 2 + 1];
    }

    // inclusive Hillis-Steele scan of affine maps (newest-on-left compose)
    #pragma unroll
    for (int d = 1; d < 64; d <<= 1) {
      float pu1 = __shfl_up(u1, d);
      float pv1 = __shfl_up(v1, d);
      float pu2 = __shfl_up(u2, d);
      float pv2 = __shfl_up(v2, d);
      float pw1 = __shfl_up(w1, d);
      float pw2 = __shfl_up(w2, d);
      bool has = (lane >= d);
      pu1 = has ? pu1 : 1.f;  pv1 = has ? pv1 : 0.f;
      pu2 = has ? pu2 : 0.f;  pv2 = has ? pv2 : 1.f;
      pw1 = has ? pw1 : 0.f;  pw2 = has ? pw2 : 0.f;
      float nu1 = fmaf(u1, pu1, v1 * pu2);
      float nv1 = fmaf(u1, pv1, v1 * pv2);
      float nu2 = fmaf(u2, pu1, v2 * pu2);
      float nv2 = fmaf(u2, pv1, v2 * pv2);
      float nw1 = fmaf(u1, pw1, fmaf(v1, pw2, w1));
      float nw2 = fmaf(u2, pw1, fmaf(v2, pw2, w2));
      u1 = nu1; v1 = nv1; u2 = nu2; v2 = nv2; w1 = nw1; w2 = nw2;
    }

    // exclusive prefix -> state entering chunk c
    float eu1 = __shfl_up(u1, 1), ev1 = __shfl_up(v1, 1);
    float eu2 = __shfl_up(u2, 1), ev2 = __shfl_up(v2, 1);
    float ew1 = __shfl_up(w1, 1), ew2 = __shfl_up(w2, 1);
    if (lane == 0) { eu1 = 1.f; ev1 = 0.f; eu2 = 0.f; ev2 = 1.f; ew1 = 0.f; ew2 = 0.f; }
    float sy1 = fmaf(eu1, cy1, fmaf(ev1, cy2, ew1));
    float sy2 = fmaf(eu2, cy1, fmaf(ev2, cy2, ew2));
    if (valid)
      *(float2*)(Sws + ((size_t)chain * C + c) * 2) = make_float2(sy1, sy2);

    // carry across groups (lanes past C-1 hold identity-composed P, so lane 63 ok)
    float ay1 = fmaf(u1, cy1, fmaf(v1, cy2, w1));
    float ay2 = fmaf(u2, cy1, fmaf(v2, cy2, w2));
    cy1 = __shfl(ay1, 63);
    cy2 = __shfl(ay2, 63);
  }

  if (lane == 0) {
    out_states[chain * 2 + 0] = cy1;
    out_states[chain * 2 + 1] = cy2;
  }
}

__global__ __launch_bounds__(256) void pass3_kernel(
    const float* __restrict__ exc, const float* __restrict__ cf,
    const float* __restrict__ bw, const float* __restrict__ Sws,
    float* __restrict__ out) {
  int tid = blockIdx.x * blockDim.x + threadIdx.x;
  if (tid >= B * C) return;
  int c = tid % C;
  int b = tid / C;

  float y1[F], y2[F];
  const float2* sp = (const float2*)Sws;
  #pragma unroll
  for (int f = 0; f < F; ++f) {
    float2 s = sp[(size_t)(b * F + f) * C + c];
    y1[f] = s.x;
    y2[f] = s.y;
  }

  int t0 = c * L;
  const float* cfp = cf + (size_t)(b * T + t0) * F;
  const float* bwp = bw + (size_t)(b * T + t0) * F;
  const float* ep  = exc + (size_t)b * T + t0;
  float* op        = out + (size_t)b * T + t0;

  #pragma unroll 2
  for (int i = 0; i < L; ++i) {
    float e = ep[i];
    float sum = 0.f;
    #pragma unroll
    for (int f = 0; f < F; ++f) {
      float bwf = bwp[(size_t)i * F + f];
      float cff = cfp[(size_t)i * F + f];
      float r  = exp2f(CBW2 * bwf);
      float th = CCF * cff;
      float sn = __sinf(th);
      float cs = __cosf(th);
      float p = 2.f * r * cs;
      float q = -r * r;
      float g = fmaf(q, sn, sn);
      float x = e * g;
      float y = fmaf(p, y1[f], fmaf(q, y2[f], x));
      sum += y;
      y2[f] = y1[f];
      y1[f] = y;
    }
    op[i] = sum;
  }
}

extern "C" void kernel_launch(void* const* d_in, const int* in_sizes, int n_in,
                              void* d_out, int out_size, void* d_ws, size_t ws_size,
                              hipStream_t stream) {
  const float* exc = (const float*)d_in[0];   // (B,T,1)
  const float* cf  = (const float*)d_in[1];   // (B,T,F)
  const float* bw  = (const float*)d_in[2];   // (B,T,F)
  const float* st  = (const float*)d_in[3];   // (B,F,2)
  float* out        = (float*)d_out;          // (B,T,1) then (B,F,2)
  float* out_states = out + (size_t)B * T;

  float* Aws = (float*)d_ws;                        // chain-major: B*F*C*8 floats = 3.84 MB
  float* Sws = Aws + (size_t)B * F * C * 8;         // chain-major: B*F*C*2 floats = 0.96 MB

  int n1 = B * C * F;
  pass1_kernel<<<(n1 + 255) / 256, 256, 0, stream>>>(exc, cf, bw, Aws);
  pass2_kernel<<<B * F, 64, 0, stream>>>(Aws, st, Sws, out_states);
  int n3 = B * C;
  pass3_kernel<<<(n3 + 255) / 256, 256, 0, stream>>>(exc, cf, bw, Sws, out);
}

// Round 3
// 64.177 us; speedup vs baseline: 2.1012x; 1.4056x over previous
//
#include <hip/hip_runtime.h>

// StatefulFormantFilter: B=32, T=48000, F=5
// y[t] = x[t] + 2 r cos(th) y[t-1] - r^2 y[t-2],  r=exp(-pi bw/SR), th=2 pi cf/SR
// x = excitation * (1-r^2) sin(th);  out = sum_f y;  new_states = (y[T-1], y[T-2])
//
// Chunked affine-scan, L=16, two-level parallel scan over chunks:
// Pass1 : per (b,f,chunk) compute chunk map (A,w) -> Aws [chain][c][8].
// Pass2a: per (chain,group-of-64) wave: Hillis-Steele inclusive scan of maps
//         IN PLACE; lane63 writes group product. Fully parallel (7520 waves).
// Pass2b: per chain: single wave-scan over NG=47 group products ->
//         group-entering states Sg + final new_states. No serial loop.
// Pass3 : per (b,chunk): entering state = scanned_map[c-1] applied to Sg[g];
//         replay 16 steps x 5 formants, register-buffer out, 4x float4 store.

constexpr int B = 32;
constexpr int T = 48000;
constexpr int F = 5;
constexpr int L = 16;          // chunk length
constexpr int C = T / L;       // 3000 chunks per chain
constexpr int GS = 64;         // chunks per scan group (one wave)
constexpr int NG = (C + GS - 1) / GS;  // 47 groups per chain
constexpr int NCHAIN = B * F;  // 160

#define CBW2 (-9.4416635e-05f)   // -pi/(48000*ln2)
#define CCF  (1.3089969e-04f)    // 2*pi/48000

__global__ __launch_bounds__(256) void pass1_kernel(
    const float* __restrict__ exc, const float* __restrict__ cf,
    const float* __restrict__ bw, float* __restrict__ Aws) {
  int tid = blockIdx.x * blockDim.x + threadIdx.x;
  if (tid >= B * C * F) return;
  int f = tid % F;
  int c = (tid / F) % C;
  int b = tid / (F * C);

  float u1 = 1.f, u2 = 0.f;
  float v1 = 0.f, v2 = 1.f;
  float w1 = 0.f, w2 = 0.f;

  int t0 = c * L;
  const float* cfp = cf + (size_t)(b * T + t0) * F + f;
  const float* bwp = bw + (size_t)(b * T + t0) * F + f;
  const float* ep  = exc + (size_t)b * T + t0;

  #pragma unroll
  for (int i = 0; i < L; ++i) {
    float bwf = bwp[(size_t)i * F];
    float cff = cfp[(size_t)i * F];
    float e   = ep[i];
    float r  = exp2f(CBW2 * bwf);
    float th = CCF * cff;
    float sn = __sinf(th);
    float cs = __cosf(th);
    float p = 2.f * r * cs;     // -a1
    float q = -r * r;           // -a2
    float g = fmaf(q, sn, sn);  // (1-r^2) sin(th)
    float x = e * g;
    float nu = fmaf(p, u1, q * u2);
    float nv = fmaf(p, v1, q * v2);
    float nw = fmaf(p, w1, fmaf(q, w2, x));
    u2 = u1; u1 = nu;
    v2 = v1; v1 = nv;
    w2 = w1; w1 = nw;
  }
  int chain = b * F + f;
  float4* o = (float4*)(Aws + ((size_t)chain * C + c) * 8);
  o[0] = make_float4(u1, u2, v1, v2);
  o[1] = make_float4(w1, w2, 0.f, 0.f);
}

// Inclusive Hillis-Steele scan of affine maps across a wave (compose newest-on-left).
__device__ inline void wave_scan_maps(int lane, float& u1, float& u2, float& v1,
                                      float& v2, float& w1, float& w2) {
  #pragma unroll
  for (int d = 1; d < 64; d <<= 1) {
    float pu1 = __shfl_up(u1, d);
    float pv1 = __shfl_up(v1, d);
    float pu2 = __shfl_up(u2, d);
    float pv2 = __shfl_up(v2, d);
    float pw1 = __shfl_up(w1, d);
    float pw2 = __shfl_up(w2, d);
    bool has = (lane >= d);
    pu1 = has ? pu1 : 1.f;  pv1 = has ? pv1 : 0.f;
    pu2 = has ? pu2 : 0.f;  pv2 = has ? pv2 : 1.f;
    pw1 = has ? pw1 : 0.f;  pw2 = has ? pw2 : 0.f;
    float nu1 = fmaf(u1, pu1, v1 * pu2);
    float nv1 = fmaf(u1, pv1, v1 * pv2);
    float nu2 = fmaf(u2, pu1, v2 * pu2);
    float nv2 = fmaf(u2, pv1, v2 * pv2);
    float nw1 = fmaf(u1, pw1, fmaf(v1, pw2, w1));
    float nw2 = fmaf(u2, pw1, fmaf(v2, pw2, w2));
    u1 = nu1; v1 = nv1; u2 = nu2; v2 = nv2; w1 = nw1; w2 = nw2;
  }
}

__global__ __launch_bounds__(256) void pass2a_kernel(
    float* __restrict__ Aws, float* __restrict__ Gprod) {
  int gwave = (blockIdx.x * blockDim.x + threadIdx.x) >> 6;
  int lane = threadIdx.x & 63;
  if (gwave >= NCHAIN * NG) return;
  int chain = gwave / NG;
  int g = gwave % NG;
  int c = g * GS + lane;
  bool valid = c < C;

  float u1 = 1.f, u2 = 0.f, v1 = 0.f, v2 = 1.f, w1 = 0.f, w2 = 0.f;
  float4* base = (float4*)(Aws + (size_t)chain * C * 8);
  if (valid) {
    float4 A0 = base[c * 2 + 0];
    float4 A1 = base[c * 2 + 1];
    u1 = A0.x; u2 = A0.y; v1 = A0.z; v2 = A0.w; w1 = A1.x; w2 = A1.y;
  }

  wave_scan_maps(lane, u1, u2, v1, v2, w1, w2);

  if (valid) {
    base[c * 2 + 0] = make_float4(u1, u2, v1, v2);
    base[c * 2 + 1] = make_float4(w1, w2, 0.f, 0.f);
  }
  if (lane == 63) {
    float4* gp = (float4*)(Gprod + (size_t)(chain * NG + g) * 8);
    gp[0] = make_float4(u1, u2, v1, v2);
    gp[1] = make_float4(w1, w2, 0.f, 0.f);
  }
}

__global__ __launch_bounds__(64) void pass2b_kernel(
    const float* __restrict__ Gprod, const float* __restrict__ states0,
    float* __restrict__ Sg, float* __restrict__ out_states) {
  int chain = blockIdx.x;
  int lane = threadIdx.x;

  float u1 = 1.f, u2 = 0.f, v1 = 0.f, v2 = 1.f, w1 = 0.f, w2 = 0.f;
  if (lane < NG) {
    const float4* gp = (const float4*)(Gprod + (size_t)(chain * NG + lane) * 8);
    float4 A0 = gp[0];
    float4 A1 = gp[1];
    u1 = A0.x; u2 = A0.y; v1 = A0.z; v2 = A0.w; w1 = A1.x; w2 = A1.y;
  }

  wave_scan_maps(lane, u1, u2, v1, v2, w1, w2);

  float s01 = states0[chain * 2 + 0];
  float s02 = states0[chain * 2 + 1];

  // exclusive prefix -> state entering group g
  float eu1 = __shfl_up(u1, 1), ev1 = __shfl_up(v1, 1);
  float eu2 = __shfl_up(u2, 1), ev2 = __shfl_up(v2, 1);
  float ew1 = __shfl_up(w1, 1), ew2 = __shfl_up(w2, 1);
  if (lane == 0) { eu1 = 1.f; ev1 = 0.f; eu2 = 0.f; ev2 = 1.f; ew1 = 0.f; ew2 = 0.f; }
  if (lane < NG) {
    float sy1 = fmaf(eu1, s01, fmaf(ev1, s02, ew1));
    float sy2 = fmaf(eu2, s01, fmaf(ev2, s02, ew2));
    *(float2*)(Sg + (size_t)(chain * NG + lane) * 2) = make_float2(sy1, sy2);
  }

  // final state (lane 63 inclusive scan includes identity pads -> full product)
  float ay1 = fmaf(u1, s01, fmaf(v1, s02, w1));
  float ay2 = fmaf(u2, s01, fmaf(v2, s02, w2));
  float fy1 = __shfl(ay1, 63);
  float fy2 = __shfl(ay2, 63);
  if (lane == 0) {
    out_states[chain * 2 + 0] = fy1;
    out_states[chain * 2 + 1] = fy2;
  }
}

__global__ __launch_bounds__(256) void pass3_kernel(
    const float* __restrict__ exc, const float* __restrict__ cf,
    const float* __restrict__ bw, const float* __restrict__ Aws,
    const float* __restrict__ Sg, float* __restrict__ out) {
  int tid = blockIdx.x * blockDim.x + threadIdx.x;
  if (tid >= B * C) return;
  int c = tid % C;
  int b = tid / C;
  int g = c >> 6;
  int lg = c & 63;

  float y1[F], y2[F];
  #pragma unroll
  for (int f = 0; f < F; ++f) {
    int chain = b * F + f;
    float2 sg = *(const float2*)(Sg + (size_t)(chain * NG + g) * 2);
    if (lg == 0) {
      y1[f] = sg.x;
      y2[f] = sg.y;
    } else {
      const float4* m = (const float4*)(Aws + ((size_t)chain * C + (c - 1)) * 8);
      float4 M0 = m[0];
      float4 M1 = m[1];
      y1[f] = fmaf(M0.x, sg.x, fmaf(M0.z, sg.y, M1.x));
      y2[f] = fmaf(M0.y, sg.x, fmaf(M0.w, sg.y, M1.y));
    }
  }

  int t0 = c * L;
  const float* cfp = cf + (size_t)(b * T + t0) * F;
  const float* bwp = bw + (size_t)(b * T + t0) * F;
  const float* ep  = exc + (size_t)b * T + t0;
  float* op        = out + (size_t)b * T + t0;

  #pragma unroll
  for (int i4 = 0; i4 < L / 4; ++i4) {
    float o4[4];
    #pragma unroll
    for (int j = 0; j < 4; ++j) {
      int i = i4 * 4 + j;
      float e = ep[i];
      float sum = 0.f;
      #pragma unroll
      for (int f = 0; f < F; ++f) {
        float bwf = bwp[(size_t)i * F + f];
        float cff = cfp[(size_t)i * F + f];
        float r  = exp2f(CBW2 * bwf);
        float th = CCF * cff;
        float sn = __sinf(th);
        float cs = __cosf(th);
        float p = 2.f * r * cs;
        float q = -r * r;
        float gn = fmaf(q, sn, sn);
        float x = e * gn;
        float y = fmaf(p, y1[f], fmaf(q, y2[f], x));
        sum += y;
        y2[f] = y1[f];
        y1[f] = y;
      }
      o4[j] = sum;
    }
    *(float4*)(op + i4 * 4) = make_float4(o4[0], o4[1], o4[2], o4[3]);
  }
}

extern "C" void kernel_launch(void* const* d_in, const int* in_sizes, int n_in,
                              void* d_out, int out_size, void* d_ws, size_t ws_size,
                              hipStream_t stream) {
  const float* exc = (const float*)d_in[0];   // (B,T,1)
  const float* cf  = (const float*)d_in[1];   // (B,T,F)
  const float* bw  = (const float*)d_in[2];   // (B,T,F)
  const float* st  = (const float*)d_in[3];   // (B,F,2)
  float* out        = (float*)d_out;          // (B,T,1) then (B,F,2)
  float* out_states = out + (size_t)B * T;

  float* Aws   = (float*)d_ws;                            // NCHAIN*C*8 floats = 15.36 MB
  float* Gprod = Aws + (size_t)NCHAIN * C * 8;            // NCHAIN*NG*8 floats = 240 KB
  float* Sg    = Gprod + (size_t)NCHAIN * NG * 8;         // NCHAIN*NG*2 floats = 60 KB

  int n1 = B * C * F;
  pass1_kernel<<<(n1 + 255) / 256, 256, 0, stream>>>(exc, cf, bw, Aws);
  int n2a = NCHAIN * NG * 64;  // one wave per (chain, group)
  pass2a_kernel<<<(n2a + 255) / 256, 256, 0, stream>>>(Aws, Gprod);
  pass2b_kernel<<<NCHAIN, 64, 0, stream>>>(Gprod, st, Sg, out_states);
  int n3 = B * C;
  pass3_kernel<<<(n3 + 255) / 256, 256, 0, stream>>>(exc, cf, bw, Aws, Sg, out);
}

// Round 4
// 53.464 us; speedup vs baseline: 2.5222x; 1.2004x over previous
//
#include <hip/hip_runtime.h>

// StatefulFormantFilter: B=32, T=48000, F=5
// y[t] = x[t] + 2 r cos(th) y[t-1] - r^2 y[t-2],  r=exp(-pi bw/SR), th=2 pi cf/SR
// x = excitation * (1-r^2) sin(th);  out = sum_f y;  new_states = (y[T-1], y[T-2])
//
// Chunked affine-scan, L=16, two-level parallel scan over chunks:
// Pass1 : per (b,f,chunk) compute chunk map (A,w) -> Aws [chain][c][8].
// Pass2a: per (chain,group-of-64) wave: in-place inclusive scan of maps;
//         lane63 writes group product.
// Pass2b: per chain: single wave-scan over NG=47 group products ->
//         group-entering states Sg + final new_states.
// Pass3 : thread=(b,chunk,f): entering state from Sg + scanned map; replay 16
//         steps of ONE formant; f-sum via padded LDS; coalesced stores.

constexpr int B = 32;
constexpr int T = 48000;
constexpr int F = 5;
constexpr int L = 16;          // chunk length
constexpr int C = T / L;       // 3000 chunks per chain
constexpr int GS = 64;         // chunks per scan group (one wave)
constexpr int NG = (C + GS - 1) / GS;  // 47 groups per chain
constexpr int NCHAIN = B * F;  // 160

#define CBW2 (-9.4416635e-05f)   // -pi/(48000*ln2)
#define CCF  (1.3089969e-04f)    // 2*pi/48000

__global__ __launch_bounds__(256) void pass1_kernel(
    const float* __restrict__ exc, const float* __restrict__ cf,
    const float* __restrict__ bw, float* __restrict__ Aws) {
  int tid = blockIdx.x * blockDim.x + threadIdx.x;
  if (tid >= B * C * F) return;
  int f = tid % F;
  int c = (tid / F) % C;
  int b = tid / (F * C);

  float u1 = 1.f, u2 = 0.f;
  float v1 = 0.f, v2 = 1.f;
  float w1 = 0.f, w2 = 0.f;

  int t0 = c * L;
  const float* cfp = cf + (size_t)(b * T + t0) * F + f;
  const float* bwp = bw + (size_t)(b * T + t0) * F + f;
  const float* ep  = exc + (size_t)b * T + t0;

  #pragma unroll
  for (int i = 0; i < L; ++i) {
    float bwf = bwp[(size_t)i * F];
    float cff = cfp[(size_t)i * F];
    float e   = ep[i];
    float r  = exp2f(CBW2 * bwf);
    float th = CCF * cff;
    float sn = __sinf(th);
    float cs = __cosf(th);
    float p = 2.f * r * cs;     // -a1
    float q = -r * r;           // -a2
    float g = fmaf(q, sn, sn);  // (1-r^2) sin(th)
    float x = e * g;
    float nu = fmaf(p, u1, q * u2);
    float nv = fmaf(p, v1, q * v2);
    float nw = fmaf(p, w1, fmaf(q, w2, x));
    u2 = u1; u1 = nu;
    v2 = v1; v1 = nv;
    w2 = w1; w1 = nw;
  }
  int chain = b * F + f;
  float4* o = (float4*)(Aws + ((size_t)chain * C + c) * 8);
  o[0] = make_float4(u1, u2, v1, v2);
  o[1] = make_float4(w1, w2, 0.f, 0.f);
}

// Inclusive Hillis-Steele scan of affine maps across a wave (compose newest-on-left).
__device__ inline void wave_scan_maps(int lane, float& u1, float& u2, float& v1,
                                      float& v2, float& w1, float& w2) {
  #pragma unroll
  for (int d = 1; d < 64; d <<= 1) {
    float pu1 = __shfl_up(u1, d);
    float pv1 = __shfl_up(v1, d);
    float pu2 = __shfl_up(u2, d);
    float pv2 = __shfl_up(v2, d);
    float pw1 = __shfl_up(w1, d);
    float pw2 = __shfl_up(w2, d);
    bool has = (lane >= d);
    pu1 = has ? pu1 : 1.f;  pv1 = has ? pv1 : 0.f;
    pu2 = has ? pu2 : 0.f;  pv2 = has ? pv2 : 1.f;
    pw1 = has ? pw1 : 0.f;  pw2 = has ? pw2 : 0.f;
    float nu1 = fmaf(u1, pu1, v1 * pu2);
    float nv1 = fmaf(u1, pv1, v1 * pv2);
    float nu2 = fmaf(u2, pu1, v2 * pu2);
    float nv2 = fmaf(u2, pv1, v2 * pv2);
    float nw1 = fmaf(u1, pw1, fmaf(v1, pw2, w1));
    float nw2 = fmaf(u2, pw1, fmaf(v2, pw2, w2));
    u1 = nu1; v1 = nv1; u2 = nu2; v2 = nv2; w1 = nw1; w2 = nw2;
  }
}

__global__ __launch_bounds__(256) void pass2a_kernel(
    float* __restrict__ Aws, float* __restrict__ Gprod) {
  int gwave = (blockIdx.x * blockDim.x + threadIdx.x) >> 6;
  int lane = threadIdx.x & 63;
  if (gwave >= NCHAIN * NG) return;
  int chain = gwave / NG;
  int g = gwave % NG;
  int c = g * GS + lane;
  bool valid = c < C;

  float u1 = 1.f, u2 = 0.f, v1 = 0.f, v2 = 1.f, w1 = 0.f, w2 = 0.f;
  float4* base = (float4*)(Aws + (size_t)chain * C * 8);
  if (valid) {
    float4 A0 = base[c * 2 + 0];
    float4 A1 = base[c * 2 + 1];
    u1 = A0.x; u2 = A0.y; v1 = A0.z; v2 = A0.w; w1 = A1.x; w2 = A1.y;
  }

  wave_scan_maps(lane, u1, u2, v1, v2, w1, w2);

  if (valid) {
    base[c * 2 + 0] = make_float4(u1, u2, v1, v2);
    base[c * 2 + 1] = make_float4(w1, w2, 0.f, 0.f);
  }
  if (lane == 63) {
    float4* gp = (float4*)(Gprod + (size_t)(chain * NG + g) * 8);
    gp[0] = make_float4(u1, u2, v1, v2);
    gp[1] = make_float4(w1, w2, 0.f, 0.f);
  }
}

__global__ __launch_bounds__(64) void pass2b_kernel(
    const float* __restrict__ Gprod, const float* __restrict__ states0,
    float* __restrict__ Sg, float* __restrict__ out_states) {
  int chain = blockIdx.x;
  int lane = threadIdx.x;

  float u1 = 1.f, u2 = 0.f, v1 = 0.f, v2 = 1.f, w1 = 0.f, w2 = 0.f;
  if (lane < NG) {
    const float4* gp = (const float4*)(Gprod + (size_t)(chain * NG + lane) * 8);
    float4 A0 = gp[0];
    float4 A1 = gp[1];
    u1 = A0.x; u2 = A0.y; v1 = A0.z; v2 = A0.w; w1 = A1.x; w2 = A1.y;
  }

  wave_scan_maps(lane, u1, u2, v1, v2, w1, w2);

  float s01 = states0[chain * 2 + 0];
  float s02 = states0[chain * 2 + 1];

  // exclusive prefix -> state entering group g
  float eu1 = __shfl_up(u1, 1), ev1 = __shfl_up(v1, 1);
  float eu2 = __shfl_up(u2, 1), ev2 = __shfl_up(v2, 1);
  float ew1 = __shfl_up(w1, 1), ew2 = __shfl_up(w2, 1);
  if (lane == 0) { eu1 = 1.f; ev1 = 0.f; eu2 = 0.f; ev2 = 1.f; ew1 = 0.f; ew2 = 0.f; }
  if (lane < NG) {
    float sy1 = fmaf(eu1, s01, fmaf(ev1, s02, ew1));
    float sy2 = fmaf(eu2, s01, fmaf(ev2, s02, ew2));
    *(float2*)(Sg + (size_t)(chain * NG + lane) * 2) = make_float2(sy1, sy2);
  }

  // final state (identity pads make lane63 hold the full product)
  float ay1 = fmaf(u1, s01, fmaf(v1, s02, w1));
  float ay2 = fmaf(u2, s01, fmaf(v2, s02, w2));
  float fy1 = __shfl(ay1, 63);
  float fy2 = __shfl(ay2, 63);
  if (lane == 0) {
    out_states[chain * 2 + 0] = fy1;
    out_states[chain * 2 + 1] = fy2;
  }
}

// Block: 320 threads = 64 chunks x 5 formants of one batch row.
// Each thread replays one formant of one chunk; f-sum via padded LDS.
constexpr int P3_CPB = 64;                 // chunks per block
constexpr int P3_THREADS = P3_CPB * F;     // 320
constexpr int P3_ROW = P3_CPB * (L + 1);   // +1 pad per chunk: conflict-free

__global__ __launch_bounds__(P3_THREADS) void pass3_kernel(
    const float* __restrict__ exc, const float* __restrict__ cf,
    const float* __restrict__ bw, const float* __restrict__ Aws,
    const float* __restrict__ Sg, float* __restrict__ out) {
  __shared__ float red[F][P3_ROW];

  int bg = blockIdx.x;
  int b = bg / NG;
  int g = bg % NG;
  int c0 = g * P3_CPB;
  int nc = (C - c0 < P3_CPB) ? (C - c0) : P3_CPB;

  int tid = threadIdx.x;
  int c_local = tid / F;
  int f = tid % F;
  bool valid = c_local < nc;

  if (valid) {
    int c = c0 + c_local;
    int chain = b * F + f;

    // entering state of chunk c
    float2 sg = *(const float2*)(Sg + (size_t)(chain * NG + g) * 2);
    float y1, y2;
    if (c_local == 0) {
      y1 = sg.x;
      y2 = sg.y;
    } else {
      const float4* m = (const float4*)(Aws + ((size_t)chain * C + (c - 1)) * 8);
      float4 M0 = m[0];
      float4 M1 = m[1];
      y1 = fmaf(M0.x, sg.x, fmaf(M0.z, sg.y, M1.x));
      y2 = fmaf(M0.y, sg.x, fmaf(M0.w, sg.y, M1.y));
    }

    int t0 = c * L;
    const float* cfp = cf + (size_t)(b * T + t0) * F + f;
    const float* bwp = bw + (size_t)(b * T + t0) * F + f;
    const float* ep  = exc + (size_t)b * T + t0;

    #pragma unroll
    for (int i = 0; i < L; ++i) {
      float bwf = bwp[(size_t)i * F];
      float cff = cfp[(size_t)i * F];
      float e   = ep[i];
      float r  = exp2f(CBW2 * bwf);
      float th = CCF * cff;
      float sn = __sinf(th);
      float cs = __cosf(th);
      float p = 2.f * r * cs;
      float q = -r * r;
      float gn = fmaf(q, sn, sn);
      float x = e * gn;
      float y = fmaf(p, y1, fmaf(q, y2, x));
      red[f][c_local * (L + 1) + i] = y;
      y2 = y1;
      y1 = y;
    }
  }

  __syncthreads();

  int nt = nc * L;
  int tbase = b * T + c0 * L;
  for (int t = tid; t < nt; t += P3_THREADS) {
    int ci = t >> 4;
    int ii = t & (L - 1);
    int a = ci * (L + 1) + ii;
    float s = red[0][a] + red[1][a] + red[2][a] + red[3][a] + red[4][a];
    out[tbase + t] = s;
  }
}

extern "C" void kernel_launch(void* const* d_in, const int* in_sizes, int n_in,
                              void* d_out, int out_size, void* d_ws, size_t ws_size,
                              hipStream_t stream) {
  const float* exc = (const float*)d_in[0];   // (B,T,1)
  const float* cf  = (const float*)d_in[1];   // (B,T,F)
  const float* bw  = (const float*)d_in[2];   // (B,T,F)
  const float* st  = (const float*)d_in[3];   // (B,F,2)
  float* out        = (float*)d_out;          // (B,T,1) then (B,F,2)
  float* out_states = out + (size_t)B * T;

  float* Aws   = (float*)d_ws;                            // NCHAIN*C*8 floats = 15.36 MB
  float* Gprod = Aws + (size_t)NCHAIN * C * 8;            // NCHAIN*NG*8 floats
  float* Sg    = Gprod + (size_t)NCHAIN * NG * 8;         // NCHAIN*NG*2 floats

  int n1 = B * C * F;
  pass1_kernel<<<(n1 + 255) / 256, 256, 0, stream>>>(exc, cf, bw, Aws);
  int n2a = NCHAIN * NG * 64;  // one wave per (chain, group)
  pass2a_kernel<<<(n2a + 255) / 256, 256, 0, stream>>>(Aws, Gprod);
  pass2b_kernel<<<NCHAIN, 64, 0, stream>>>(Gprod, st, Sg, out_states);
  pass3_kernel<<<B * NG, P3_THREADS, 0, stream>>>(exc, cf, bw, Aws, Sg, out);
}